// Round 1
// 3461.966 us; speedup vs baseline: 1.6227x; 1.6227x over previous
//
#include <hip/hip_runtime.h>
#include <hip/hip_bf16.h>
#include <stdint.h>

typedef __bf16 bf16_t;
typedef bf16_t bf16x8 __attribute__((ext_vector_type(8)));
typedef float  f32x4  __attribute__((ext_vector_type(4)));
typedef float  f32x16 __attribute__((ext_vector_type(16)));

#define I_DIM 512
#define H_DIM 1024
#define B_DIM 64
#define S_DIM 512
#define G4    4096   // 4*H
#define CHUNK 32     // xproj steps per chunk
#define NCHUNK (S_DIM / CHUNK)

// ---------------- workspace layout (bytes) — total ~34 MB ----------------
#define O_WXT   0x0000000ULL  // [4096][512]  bf16 = 4 MB   (packed WxT, row-major)
#define O_WHTF  0x0400000ULL  // [128][64][64][8] bf16 = 8 MB (Wh in MFMA B-frag order)
#define O_BIAS  0x0C00000ULL  // [4096] f32 = 16 KB
#define O_CST   0x0C10000ULL  // [64][1024] f32 = 256 KB (c-state, address-stable)
#define O_HBUF  0x0D00000ULL  // 2 slots * 128 KB (h in A-frag order) = 256 KB
#define O_XP    0x1200000ULL  // [CHUNK*64][4096] bf16 = 16 MB

__device__ __forceinline__ float sigm(float x)      { return 1.f / (1.f + __expf(-x)); }
__device__ __forceinline__ float tanh_fast(float x) { return 1.f - 2.f / (__expf(2.f * x) + 1.f); }

// Packed gate-column permutation: packed col p = q*32 + g*8 + jj  <->  hidden j = q*8+jj, gate g (0:i 1:f 2:g 3:o)

__global__ void k_pack_wx(const float* __restrict__ w0, const float* __restrict__ w1,
                          const float* __restrict__ w2, const float* __restrict__ w3,
                          bf16_t* __restrict__ wxt) {
    int tid = blockIdx.x * 256 + threadIdx.x;
    int k = tid >> 12;
    int p = tid & 4095;
    int q = p >> 5, g = (p >> 3) & 3, jj = p & 7;
    int j = q * 8 + jj;
    const float* src = (g == 0) ? w0 : (g == 1) ? w1 : (g == 2) ? w2 : w3;
    wxt[(size_t)p * I_DIM + k] = (bf16_t)src[k * H_DIM + j];
}

// Wh -> global MFMA B-fragment order: whtf[q][ks][lane][8]
//   element = WhT[p = q*32 + (lane&31)][k = ks*16 + (lane>>5)*8 + e]
__global__ void k_pack_whf(const float* __restrict__ w0, const float* __restrict__ w1,
                           const float* __restrict__ w2, const float* __restrict__ w3,
                           bf16_t* __restrict__ whtf) {
    int idx = blockIdx.x * 256 + threadIdx.x;     // 0..4194303
    int e    = idx & 7;
    int lane = (idx >> 3) & 63;
    int ks   = (idx >> 9) & 63;
    int q    = idx >> 15;                          // 0..127
    int k = ks * 16 + (lane >> 5) * 8 + e;
    int c = lane & 31;
    int g = c >> 3, jj = c & 7;
    int j = q * 8 + jj;
    const float* src = (g == 0) ? w0 : (g == 1) ? w1 : (g == 2) ? w2 : w3;
    whtf[idx] = (bf16_t)src[k * H_DIM + j];
}

__global__ void k_pack_bias(const float* bi0, const float* bh0, const float* bi1, const float* bh1,
                            const float* bi2, const float* bh2, const float* bi3, const float* bh3,
                            float* __restrict__ bias) {
    int p = blockIdx.x * 256 + threadIdx.x;
    int q = p >> 5, g = (p >> 3) & 3, jj = p & 7;
    int j = q * 8 + jj;
    const float* a = (g == 0) ? bi0 : (g == 1) ? bi1 : (g == 2) ? bi2 : bi3;
    const float* b = (g == 0) ? bh0 : (g == 1) ? bh1 : (g == 2) ? bh2 : bh3;
    bias[p] = a[j] + b[j];
}

// ---------------- chunked x_proj GEMM (unchanged) ----------------
__global__ __launch_bounds__(256, 2) void k_xproj(
    const float* __restrict__ x, const bf16_t* __restrict__ wxt,
    const float* __restrict__ bias, bf16_t* __restrict__ xp, int r_base)
{
    __shared__ __align__(16) bf16_t Al[8 * 64 * 8];
    __shared__ __align__(16) bf16_t Bl[8 * 64 * 8];
    const int tid = threadIdx.x;
    const int n0 = blockIdx.x * 128;
    const int r0 = r_base + blockIdx.y * 128;
    const int wv = tid >> 6;
    const int lane = tid & 63;
    const int mq = wv >> 1, nq = wv & 1;
    f32x4 acc[4][4] = {};

    for (int kk = 0; kk < I_DIM; kk += 32) {
        __syncthreads();
        #pragma unroll
        for (int sidx = 0; sidx < 2; ++sidx) {
            int s = tid + sidx * 256;
            int mt = s >> 6, l = s & 63;
            int m = l & 15, kb = (l >> 4) * 8;
            int r = r0 + mt * 16 + m;
            int b = r & 63, si = r >> 6;
            const float* gp = x + ((size_t)(b * S_DIM + si)) * I_DIM + kk + kb;
            float4 v0 = *(const float4*)gp;
            float4 v1 = *(const float4*)(gp + 4);
            bf16x8 a;
            a[0] = (bf16_t)v0.x; a[1] = (bf16_t)v0.y; a[2] = (bf16_t)v0.z; a[3] = (bf16_t)v0.w;
            a[4] = (bf16_t)v1.x; a[5] = (bf16_t)v1.y; a[6] = (bf16_t)v1.z; a[7] = (bf16_t)v1.w;
            *(bf16x8*)&Al[s * 8] = a;
            bf16x8 bv = *(const bf16x8*)(wxt + (size_t)(n0 + mt * 16 + m) * I_DIM + kk + kb);
            *(bf16x8*)&Bl[s * 8] = bv;
        }
        __syncthreads();
        bf16x8 af[4], bfr[4];
        #pragma unroll
        for (int mt = 0; mt < 4; ++mt) af[mt]  = *(bf16x8*)&Al[((mq * 4 + mt) * 64 + lane) * 8];
        #pragma unroll
        for (int nt = 0; nt < 4; ++nt) bfr[nt] = *(bf16x8*)&Bl[((nq * 4 + nt) * 64 + lane) * 8];
        #pragma unroll
        for (int mt = 0; mt < 4; ++mt)
            #pragma unroll
            for (int nt = 0; nt < 4; ++nt)
                acc[mt][nt] = __builtin_amdgcn_mfma_f32_16x16x32_bf16(af[mt], bfr[nt], acc[mt][nt], 0, 0, 0);
    }
    const int l15 = lane & 15, quad = lane >> 4;
    #pragma unroll
    for (int nt = 0; nt < 4; ++nt) {
        int col = n0 + nq * 64 + nt * 16 + l15;
        float bv = bias[col];
        #pragma unroll
        for (int mt = 0; mt < 4; ++mt)
            #pragma unroll
            for (int r = 0; r < 4; ++r) {
                int row = r0 - r_base + mq * 64 + mt * 16 + quad * 4 + r;
                xp[(size_t)row * G4 + col] = (bf16_t)(acc[mt][nt][r] + bv);
            }
    }
}

// ---------------- one LSTM time-step per launch ----------------
// R7: latency attack. Old shape: 64 WGs (64 CUs, 1 wave/SIMD), each wave a
// full K=1024 chain = 64 serial iters with an 8-deep prefetch (~80 cyc of
// cover vs ~600-900 cyc L3 latency on the h stream) -> ~8 us exec.
// New shape: 256 WGs (all CUs). WG (q, bh) owns one 32x32 output tile;
// wave kq takes K-quarter kq*256. Each wave's 16 A-frags + 16 B-frags are
// issued UPFRONT (32 outstanding 1KB loads -> one latency exposure), 16
// MFMA in 4 chains, LDS cross-wave reduce in conflict-free [w][reg][lane]
// b32 layout, epilogue parallelized 4x (wave w handles acc regs 4w..4w+3).
// bid mapping: q = bid&127, bh = bid>>7 -> the two WGs sharing a whtf
// slice are 128 apart == same XCD under round-robin -> one L2 fill.
// Kernel boundary still = device barrier (in-kernel device-scope barrier
// measured 11-14 us/step in R2-R6; keep the ~2 us AQL gap instead).
__global__ __launch_bounds__(256, 1) void k_step(
    const bf16_t* __restrict__ whtf, const bf16_t* __restrict__ xp_t,
    const bf16_t* __restrict__ h_t, bf16_t* __restrict__ h_n,
    float* __restrict__ cstbuf, float* __restrict__ out, int write_out)
{
    __shared__ float Pl[4][16][64];               // partials [wave][reg][lane], 16 KB
    __shared__ __align__(16) bf16_t Hlds[256];    // h staging for coalesced store
    const int tid  = threadIdx.x;
    const int w    = tid >> 6;                    // K-quarter index
    const int lane = tid & 63;
    const int bid  = blockIdx.x;
    const int q    = bid & 127;                   // packed col-block (32 cols)
    const int bh   = bid >> 7;                    // batch half

    const int col  = lane & 31;
    const int ksel = lane >> 5;
    const int gt   = (lane >> 3) & 3;  // 0:i 1:f 2:g 3:o
    const int jj   = lane & 7;

    // C-frag rows this wave owns after the reduce: acc reg r=4w+e -> row
    int rrow[4];
    #pragma unroll
    for (int e = 0; e < 4; ++e) rrow[e] = e + 8 * w + 4 * ksel;

    // xp + c-state loads (issue early, consumed in epilogue)
    bf16_t xpr[4];
    #pragma unroll
    for (int e = 0; e < 4; ++e)
        xpr[e] = xp_t[(size_t)(bh * 32 + rrow[e]) * G4 + q * 32 + col];
    float cst[4];
    if (gt == 0) {
        #pragma unroll
        for (int e = 0; e < 4; ++e)
            cst[e] = cstbuf[(bh * 32 + rrow[e]) * H_DIM + q * 8 + jj];
    }

    // A (h, frag order) and B (whtf, frag order) bases for this K-quarter
    const bf16_t* ab = h_t  + (bh << 15) + (w << 13) + (lane << 3);
    const bf16_t* bb = whtf + ((size_t)q << 15) + (w << 13) + (lane << 3);

    // All 32 fragment loads upfront: one L3/L2 latency exposure, max MLP.
    bf16x8 ar[16], br[16];
    #pragma unroll
    for (int i = 0; i < 16; ++i) {
        ar[i] = *(const bf16x8*)(ab + i * 512);
        br[i] = *(const bf16x8*)(bb + i * 512);
    }
    f32x16 acc0 = {}, acc1 = {}, acc2 = {}, acc3 = {};
    #pragma unroll
    for (int i = 0; i < 16; i += 4) {
        acc0 = __builtin_amdgcn_mfma_f32_32x32x16_bf16(ar[i + 0], br[i + 0], acc0, 0, 0, 0);
        acc1 = __builtin_amdgcn_mfma_f32_32x32x16_bf16(ar[i + 1], br[i + 1], acc1, 0, 0, 0);
        acc2 = __builtin_amdgcn_mfma_f32_32x32x16_bf16(ar[i + 2], br[i + 2], acc2, 0, 0, 0);
        acc3 = __builtin_amdgcn_mfma_f32_32x32x16_bf16(ar[i + 3], br[i + 3], acc3, 0, 0, 0);
    }
    f32x16 accs = acc0 + acc1 + acc2 + acc3;

    // Publish this wave's K-quarter partial: [w][reg][lane] b32, conflict-free.
    #pragma unroll
    for (int e = 0; e < 16; ++e) Pl[w][e][lane] = accs[e];
    __syncthreads();

    // Wave w reduces acc regs 4w..4w+3 across the 4 K-quarters.
    // (All via LDS reads — no runtime indexing into f32x16 regs.)
    #pragma unroll
    for (int e = 0; e < 4; ++e) {
        int eg = w * 4 + e;
        float pre = Pl[0][eg][lane] + Pl[1][eg][lane] + Pl[2][eg][lane] + Pl[3][eg][lane];
        pre += (float)xpr[e];
        float a = (gt == 2) ? tanh_fast(pre) : sigm(pre);

        float fv = __shfl_xor(a, 8, 64);
        float gv = __shfl_xor(a, 16, 64);
        float ov = __shfl_xor(a, 24, 64);
        if (gt == 0) {
            float cn = fv * cst[e] + a * gv;
            float hv = ov * tanh_fast(cn);
            Hlds[rrow[e] * 8 + jj] = (bf16_t)hv;
            cstbuf[(bh * 32 + rrow[e]) * H_DIM + q * 8 + jj] = cn;
            if (write_out) {
                int rowg = bh * 32 + rrow[e];
                int j = q * 8 + jj;
                out[rowg * H_DIM + j] = hv;            // h_T
                out[65536 + rowg * H_DIM + j] = cn;    // c_T
            }
        }
    }
    __syncthreads();

    // h_n write: this WG's output = contiguous 512 B in A-frag layout.
    if (w == 0) {
        uint64_t v = *(const uint64_t*)&Hlds[lane * 4];
        ((uint64_t*)h_n)[(bh << 13) + (q << 6) + lane] = v;
    }
}

extern "C" void kernel_launch(void* const* d_in, const int* in_sizes, int n_in,
                              void* d_out, int out_size, void* d_ws, size_t ws_size,
                              hipStream_t stream) {
    const float* x   = (const float*)d_in[0];
    const float* wii = (const float*)d_in[1];
    const float* bii = (const float*)d_in[2];
    const float* whi = (const float*)d_in[3];
    const float* bhi = (const float*)d_in[4];
    const float* wif = (const float*)d_in[5];
    const float* bif = (const float*)d_in[6];
    const float* whf = (const float*)d_in[7];
    const float* bhf = (const float*)d_in[8];
    const float* wig = (const float*)d_in[9];
    const float* big = (const float*)d_in[10];
    const float* whg = (const float*)d_in[11];
    const float* bhg = (const float*)d_in[12];
    const float* wio = (const float*)d_in[13];
    const float* bio = (const float*)d_in[14];
    const float* who = (const float*)d_in[15];
    const float* bho = (const float*)d_in[16];

    char* ws = (char*)d_ws;
    bf16_t*  wxt   = (bf16_t*)(ws + O_WXT);
    bf16_t*  whtf  = (bf16_t*)(ws + O_WHTF);
    float*   bias  = (float*)(ws + O_BIAS);
    float*   cstb  = (float*)(ws + O_CST);
    bf16_t*  hbuf  = (bf16_t*)(ws + O_HBUF);
    bf16_t*  xp    = (bf16_t*)(ws + O_XP);

    hipMemsetAsync(hbuf, 0, 128 * 1024, stream);   // h0 = 0 (slot 0, frag order)
    hipMemsetAsync(cstb, 0, 256 * 1024, stream);   // c0 = 0

    k_pack_wx<<<8192, 256, 0, stream>>>(wii, wif, wig, wio, wxt);
    k_pack_whf<<<16384, 256, 0, stream>>>(whi, whf, whg, who, whtf);
    k_pack_bias<<<16, 256, 0, stream>>>(bii, bhi, bif, bhf, big, bhg, bio, bho, bias);

    float* out = (float*)d_out;
    for (int c = 0; c < NCHUNK; ++c) {
        k_xproj<<<dim3(32, CHUNK * 64 / 128), 256, 0, stream>>>(x, wxt, bias, xp, c * CHUNK * 64);
        for (int tl = 0; tl < CHUNK; ++tl) {
            int t = c * CHUNK + tl;
            k_step<<<256, 256, 0, stream>>>(
                whtf, xp + (size_t)tl * 64 * G4,
                hbuf + (size_t)(t & 1) * 65536,
                hbuf + (size_t)((t + 1) & 1) * 65536,
                cstb, out, (t == S_DIM - 1) ? 1 : 0);
        }
    }
}

// Round 2
// 3343.510 us; speedup vs baseline: 1.6802x; 1.0354x over previous
//
#include <hip/hip_runtime.h>
#include <hip/hip_bf16.h>
#include <stdint.h>

typedef __bf16 bf16_t;
typedef bf16_t bf16x8 __attribute__((ext_vector_type(8)));
typedef float  f32x4  __attribute__((ext_vector_type(4)));
typedef float  f32x16 __attribute__((ext_vector_type(16)));

#define I_DIM 512
#define H_DIM 1024
#define B_DIM 64
#define S_DIM 512
#define G4    4096   // 4*H
#define CHUNK 32     // xproj steps per chunk == steps per persistent dispatch
#define NCHUNK (S_DIM / CHUNK)

// ---------------- workspace layout (bytes) — total ~34 MB ----------------
#define O_WXT   0x0000000ULL  // [4096][512]  bf16 = 4 MB   (packed WxT, row-major)
#define O_WHTF  0x0400000ULL  // [128][64][64][8] bf16 = 8 MB (Wh in MFMA B-frag order)
#define O_BIAS  0x0C00000ULL  // [4096] f32 = 16 KB
#define O_CST   0x0C10000ULL  // [64][1024] f32 = 256 KB (c-state, chunk-boundary only)
#define O_HBUF  0x0D00000ULL  // 2 slots * 128 KB (h in A-frag order) = 256 KB
#define O_BAR   0x0D40000ULL  // 4 KB grid-barrier state (monotonic counters)
#define O_XP    0x1200000ULL  // [CHUNK*64][4096] bf16 = 16 MB

__device__ __forceinline__ float sigm(float x)      { return 1.f / (1.f + __expf(-x)); }
__device__ __forceinline__ float tanh_fast(float x) { return 1.f - 2.f / (__expf(2.f * x) + 1.f); }

// Packed gate-column permutation: packed col p = q*32 + g*8 + jj  <->  hidden j = q*8+jj, gate g (0:i 1:f 2:g 3:o)

__global__ void k_pack_wx(const float* __restrict__ w0, const float* __restrict__ w1,
                          const float* __restrict__ w2, const float* __restrict__ w3,
                          bf16_t* __restrict__ wxt) {
    int tid = blockIdx.x * 256 + threadIdx.x;
    int k = tid >> 12;
    int p = tid & 4095;
    int q = p >> 5, g = (p >> 3) & 3, jj = p & 7;
    int j = q * 8 + jj;
    const float* src = (g == 0) ? w0 : (g == 1) ? w1 : (g == 2) ? w2 : w3;
    wxt[(size_t)p * I_DIM + k] = (bf16_t)src[k * H_DIM + j];
}

// Wh -> global MFMA B-fragment order: whtf[q][ks][lane][8]
//   element = WhT[p = q*32 + (lane&31)][k = ks*16 + (lane>>5)*8 + e]
__global__ void k_pack_whf(const float* __restrict__ w0, const float* __restrict__ w1,
                           const float* __restrict__ w2, const float* __restrict__ w3,
                           bf16_t* __restrict__ whtf) {
    int idx = blockIdx.x * 256 + threadIdx.x;     // 0..4194303
    int e    = idx & 7;
    int lane = (idx >> 3) & 63;
    int ks   = (idx >> 9) & 63;
    int q    = idx >> 15;                          // 0..127
    int k = ks * 16 + (lane >> 5) * 8 + e;
    int c = lane & 31;
    int g = c >> 3, jj = c & 7;
    int j = q * 8 + jj;
    const float* src = (g == 0) ? w0 : (g == 1) ? w1 : (g == 2) ? w2 : w3;
    whtf[idx] = (bf16_t)src[k * H_DIM + j];
}

__global__ void k_pack_bias(const float* bi0, const float* bh0, const float* bi1, const float* bh1,
                            const float* bi2, const float* bh2, const float* bi3, const float* bh3,
                            float* __restrict__ bias) {
    int p = blockIdx.x * 256 + threadIdx.x;
    int q = p >> 5, g = (p >> 3) & 3, jj = p & 7;
    int j = q * 8 + jj;
    const float* a = (g == 0) ? bi0 : (g == 1) ? bi1 : (g == 2) ? bi2 : bi3;
    const float* b = (g == 0) ? bh0 : (g == 1) ? bh1 : (g == 2) ? bh2 : bh3;
    bias[p] = a[j] + b[j];
}

// ---------------- chunked x_proj GEMM (unchanged) ----------------
__global__ __launch_bounds__(256, 2) void k_xproj(
    const float* __restrict__ x, const bf16_t* __restrict__ wxt,
    const float* __restrict__ bias, bf16_t* __restrict__ xp, int r_base)
{
    __shared__ __align__(16) bf16_t Al[8 * 64 * 8];
    __shared__ __align__(16) bf16_t Bl[8 * 64 * 8];
    const int tid = threadIdx.x;
    const int n0 = blockIdx.x * 128;
    const int r0 = r_base + blockIdx.y * 128;
    const int wv = tid >> 6;
    const int lane = tid & 63;
    const int mq = wv >> 1, nq = wv & 1;
    f32x4 acc[4][4] = {};

    for (int kk = 0; kk < I_DIM; kk += 32) {
        __syncthreads();
        #pragma unroll
        for (int sidx = 0; sidx < 2; ++sidx) {
            int s = tid + sidx * 256;
            int mt = s >> 6, l = s & 63;
            int m = l & 15, kb = (l >> 4) * 8;
            int r = r0 + mt * 16 + m;
            int b = r & 63, si = r >> 6;
            const float* gp = x + ((size_t)(b * S_DIM + si)) * I_DIM + kk + kb;
            float4 v0 = *(const float4*)gp;
            float4 v1 = *(const float4*)(gp + 4);
            bf16x8 a;
            a[0] = (bf16_t)v0.x; a[1] = (bf16_t)v0.y; a[2] = (bf16_t)v0.z; a[3] = (bf16_t)v0.w;
            a[4] = (bf16_t)v1.x; a[5] = (bf16_t)v1.y; a[6] = (bf16_t)v1.z; a[7] = (bf16_t)v1.w;
            *(bf16x8*)&Al[s * 8] = a;
            bf16x8 bv = *(const bf16x8*)(wxt + (size_t)(n0 + mt * 16 + m) * I_DIM + kk + kb);
            *(bf16x8*)&Bl[s * 8] = bv;
        }
        __syncthreads();
        bf16x8 af[4], bfr[4];
        #pragma unroll
        for (int mt = 0; mt < 4; ++mt) af[mt]  = *(bf16x8*)&Al[((mq * 4 + mt) * 64 + lane) * 8];
        #pragma unroll
        for (int nt = 0; nt < 4; ++nt) bfr[nt] = *(bf16x8*)&Bl[((nq * 4 + nt) * 64 + lane) * 8];
        #pragma unroll
        for (int mt = 0; mt < 4; ++mt)
            #pragma unroll
            for (int nt = 0; nt < 4; ++nt)
                acc[mt][nt] = __builtin_amdgcn_mfma_f32_16x16x32_bf16(af[mt], bfr[nt], acc[mt][nt], 0, 0, 0);
    }
    const int l15 = lane & 15, quad = lane >> 4;
    #pragma unroll
    for (int nt = 0; nt < 4; ++nt) {
        int col = n0 + nq * 64 + nt * 16 + l15;
        float bv = bias[col];
        #pragma unroll
        for (int mt = 0; mt < 4; ++mt)
            #pragma unroll
            for (int r = 0; r < 4; ++r) {
                int row = r0 - r_base + mq * 64 + mt * 16 + quad * 4 + r;
                xp[(size_t)row * G4 + col] = (bf16_t)(acc[mt][nt][r] + bv);
            }
    }
}

// ---------------- 32 LSTM time-steps per persistent dispatch ----------------
// R8: launch-overhead attack. R6/R7 data fit slot = gap(~4.5-5us) + exec:
// R7 exec ~1.3us << slot 6.1us -> per-dispatch overhead dominates (~2.5ms
// of 3.46ms). Fuse CHUNK=32 steps into one cooperative dispatch.
// Why this barrier should NOT cost R2-R6's 11-14us: zero cache-maintenance.
// All cross-step h traffic uses agent-scope relaxed atomics (sc0 sc1:
// write-through past L2, L2-bypassing loads -> coherent at L3 by
// construction). Release = __syncthreads()'s implicit s_waitcnt vmcnt(0).
// Barrier = hierarchical monotonic counters (8 groups x 32 WGs -> root x8
// -> epoch), ~1-1.5us. Enabled by fusion: B-frags (whtf) loop-invariant ->
// loaded ONCE into 64 VGPRs for all 32 steps; c-state in registers for the
// whole chunk (chunk-boundary load/store only). Per-step traffic = h only
// (64 KB/CU from L3) + xp scalars.
__global__ __launch_bounds__(256, 1) void k_steps(
    const bf16_t* __restrict__ whtf, const bf16_t* __restrict__ xp_c,
    bf16_t* __restrict__ hbuf, float* __restrict__ cstbuf,
    float* __restrict__ out, uint32_t* __restrict__ bar,
    int t_base, int ep_base, int write_out_last)
{
    __shared__ float Pl[4][16][64];               // partials [wave][reg][lane], 16 KB
    __shared__ __align__(16) bf16_t Hlds[256];    // h staging for the frag-order store
    const int tid  = threadIdx.x;
    const int w    = tid >> 6;                    // K-quarter index
    const int lane = tid & 63;
    const int bid  = blockIdx.x;
    const int q    = bid & 127;                   // packed col-block (32 cols)
    const int bh   = bid >> 7;                    // batch half

    const int col  = lane & 31;
    const int ksel = lane >> 5;
    const int gt   = (lane >> 3) & 3;  // 0:i 1:f 2:g 3:o
    const int jj   = lane & 7;

    int rrow[4];
    #pragma unroll
    for (int e = 0; e < 4; ++e) rrow[e] = e + 8 * w + 4 * ksel;

    // Loop-invariant B fragments: cached loads once, live in VGPRs all chunk.
    const bf16_t* bb = whtf + ((size_t)q << 15) + (w << 13) + (lane << 3);
    bf16x8 bfr[16];
    #pragma unroll
    for (int i = 0; i < 16; ++i) bfr[i] = *(const bf16x8*)(bb + i * 512);

    // c-state in registers for the whole chunk (i-gate lanes only).
    float cst[4] = {0.f, 0.f, 0.f, 0.f};
    if (gt == 0) {
        #pragma unroll
        for (int e = 0; e < 4; ++e)
            cst[e] = cstbuf[(bh * 32 + rrow[e]) * H_DIM + q * 8 + jj];
    }

    const int abase = (bh << 15) + (w << 13) + (lane << 3);  // h A-frag base (elements)

    for (int tl = 0; tl < CHUNK; ++tl) {
        const bf16_t* xp_t = xp_c + (size_t)(tl * 64) * G4;
        uint64_t* hsrc = (uint64_t*)(hbuf + (((t_base + tl) & 1) << 16) + abase);

        // Upfront agent-scope h loads (L2-bypassing -> L3-fresh). 32 dwordx2.
        uint64_t hl0[16], hl1[16];
        #pragma unroll
        for (int i = 0; i < 16; ++i) {
            hl0[i] = __hip_atomic_load(hsrc + i * 128,     __ATOMIC_RELAXED, __HIP_MEMORY_SCOPE_AGENT);
            hl1[i] = __hip_atomic_load(hsrc + i * 128 + 1, __ATOMIC_RELAXED, __HIP_MEMORY_SCOPE_AGENT);
        }

        bf16_t xpr[4];
        #pragma unroll
        for (int e = 0; e < 4; ++e)
            xpr[e] = xp_t[(size_t)(bh * 32 + rrow[e]) * G4 + q * 32 + col];

        struct U2 { uint64_t a, b; };
        f32x16 acc0 = {}, acc1 = {}, acc2 = {}, acc3 = {};
        #pragma unroll
        for (int i = 0; i < 16; i += 4) {
            U2 t0{hl0[i + 0], hl1[i + 0]};
            U2 t1{hl0[i + 1], hl1[i + 1]};
            U2 t2{hl0[i + 2], hl1[i + 2]};
            U2 t3{hl0[i + 3], hl1[i + 3]};
            acc0 = __builtin_amdgcn_mfma_f32_32x32x16_bf16(__builtin_bit_cast(bf16x8, t0), bfr[i + 0], acc0, 0, 0, 0);
            acc1 = __builtin_amdgcn_mfma_f32_32x32x16_bf16(__builtin_bit_cast(bf16x8, t1), bfr[i + 1], acc1, 0, 0, 0);
            acc2 = __builtin_amdgcn_mfma_f32_32x32x16_bf16(__builtin_bit_cast(bf16x8, t2), bfr[i + 2], acc2, 0, 0, 0);
            acc3 = __builtin_amdgcn_mfma_f32_32x32x16_bf16(__builtin_bit_cast(bf16x8, t3), bfr[i + 3], acc3, 0, 0, 0);
        }
        f32x16 accs = acc0 + acc1 + acc2 + acc3;

        #pragma unroll
        for (int e = 0; e < 16; ++e) Pl[w][e][lane] = accs[e];
        __syncthreads();

        #pragma unroll
        for (int e = 0; e < 4; ++e) {
            int eg = w * 4 + e;
            float pre = Pl[0][eg][lane] + Pl[1][eg][lane] + Pl[2][eg][lane] + Pl[3][eg][lane];
            pre += (float)xpr[e];
            float a = (gt == 2) ? tanh_fast(pre) : sigm(pre);

            float fv = __shfl_xor(a, 8, 64);
            float gv = __shfl_xor(a, 16, 64);
            float ov = __shfl_xor(a, 24, 64);
            if (gt == 0) {
                float cn = fv * cst[e] + a * gv;
                float hv = ov * tanh_fast(cn);
                cst[e] = cn;
                Hlds[rrow[e] * 8 + jj] = (bf16_t)hv;
                if (write_out_last && tl == CHUNK - 1) {
                    int rowg = bh * 32 + rrow[e];
                    int j = q * 8 + jj;
                    out[rowg * H_DIM + j] = hv;            // h_T
                    out[65536 + rowg * H_DIM + j] = cn;    // c_T
                }
            }
        }
        __syncthreads();   // Hlds ready; Pl reusable next step

        if (w == 0) {
            uint64_t v = *(const uint64_t*)&Hlds[lane * 4];
            uint64_t* hdst = (uint64_t*)(hbuf + (((t_base + tl + 1) & 1) << 16));
            __hip_atomic_store(hdst + (bh << 13) + (q << 6) + lane, v,
                               __ATOMIC_RELAXED, __HIP_MEMORY_SCOPE_AGENT);
        }

        if (tl < CHUNK - 1) {
            __syncthreads();   // implicit vmcnt(0): wave0's h store drained to L3
            if (tid == 0) {
                uint32_t old = __hip_atomic_fetch_add(&bar[(bid & 7) * 64], 1u,
                                                      __ATOMIC_RELAXED, __HIP_MEMORY_SCOPE_AGENT);
                if ((old & 31u) == 31u) {                   // group leader (32 arrivals)
                    uint32_t old2 = __hip_atomic_fetch_add(&bar[512], 1u,
                                                           __ATOMIC_RELAXED, __HIP_MEMORY_SCOPE_AGENT);
                    if ((old2 & 7u) == 7u)                  // last of 8 groups
                        __hip_atomic_fetch_add(&bar[576], 1u,
                                               __ATOMIC_RELAXED, __HIP_MEMORY_SCOPE_AGENT);
                }
                uint32_t target = (uint32_t)(ep_base + tl + 1);
                while (__hip_atomic_load(&bar[576], __ATOMIC_RELAXED, __HIP_MEMORY_SCOPE_AGENT) < target) {}
            }
            __syncthreads();
        }
    }

    // c-state writeback for the next chunk (normal stores; dispatch-end release)
    if (gt == 0) {
        #pragma unroll
        for (int e = 0; e < 4; ++e)
            cstbuf[(bh * 32 + rrow[e]) * H_DIM + q * 8 + jj] = cst[e];
    }
}

extern "C" void kernel_launch(void* const* d_in, const int* in_sizes, int n_in,
                              void* d_out, int out_size, void* d_ws, size_t ws_size,
                              hipStream_t stream) {
    const float* x   = (const float*)d_in[0];
    const float* wii = (const float*)d_in[1];
    const float* bii = (const float*)d_in[2];
    const float* whi = (const float*)d_in[3];
    const float* bhi = (const float*)d_in[4];
    const float* wif = (const float*)d_in[5];
    const float* bif = (const float*)d_in[6];
    const float* whf = (const float*)d_in[7];
    const float* bhf = (const float*)d_in[8];
    const float* wig = (const float*)d_in[9];
    const float* big = (const float*)d_in[10];
    const float* whg = (const float*)d_in[11];
    const float* bhg = (const float*)d_in[12];
    const float* wio = (const float*)d_in[13];
    const float* bio = (const float*)d_in[14];
    const float* who = (const float*)d_in[15];
    const float* bho = (const float*)d_in[16];

    char* ws = (char*)d_ws;
    bf16_t*   wxt  = (bf16_t*)(ws + O_WXT);
    bf16_t*   whtf = (bf16_t*)(ws + O_WHTF);
    float*    bias = (float*)(ws + O_BIAS);
    float*    cstb = (float*)(ws + O_CST);
    bf16_t*   hbuf = (bf16_t*)(ws + O_HBUF);
    uint32_t* bar  = (uint32_t*)(ws + O_BAR);
    bf16_t*   xp   = (bf16_t*)(ws + O_XP);

    hipMemsetAsync(hbuf, 0, 128 * 1024, stream);   // h0 = 0 (slot 0, frag order)
    hipMemsetAsync(cstb, 0, 256 * 1024, stream);   // c0 = 0
    hipMemsetAsync(bar,  0, 4096, stream);         // barrier counters (reset each graph replay)

    k_pack_wx<<<8192, 256, 0, stream>>>(wii, wif, wig, wio, wxt);
    k_pack_whf<<<16384, 256, 0, stream>>>(whi, whf, whg, who, whtf);
    k_pack_bias<<<16, 256, 0, stream>>>(bii, bhi, bif, bhf, big, bhg, bio, bho, bias);

    float* out = (float*)d_out;
    for (int c = 0; c < NCHUNK; ++c) {
        k_xproj<<<dim3(32, CHUNK * 64 / 128), 256, 0, stream>>>(x, wxt, bias, xp, c * CHUNK * 64);
        int t_base  = c * CHUNK;
        int ep_base = c * (CHUNK - 1);
        int wol     = (c == NCHUNK - 1) ? 1 : 0;
        void* args[] = { (void*)&whtf, (void*)&xp, (void*)&hbuf, (void*)&cstb,
                         (void*)&out, (void*)&bar, (void*)&t_base, (void*)&ep_base, (void*)&wol };
        hipError_t err = hipLaunchCooperativeKernel((const void*)k_steps, dim3(256), dim3(256),
                                                    args, 0, stream);
        if (err != hipSuccess) {
            // Fallback: plain launch. 256 WGs at 1 WG/CU are co-resident on a
            // 256-CU MI355X; barrier semantics identical.
            k_steps<<<256, 256, 0, stream>>>(whtf, xp, hbuf, cstb, out, bar,
                                             t_base, ep_base, wol);
        }
    }
}